// Round 11
// baseline (596.579 us; speedup 1.0000x reference)
//
#include <hip/hip_runtime.h>
#include <hip/hip_fp16.h>

constexpr int NN = 100000;   // nodes (== 6250 * 16, no remainder)
constexpr int NE = 1250000;  // edges
constexpr int KDIM = 128;    // IN_DIM
constexpr int HID = 64;

using half8   = __attribute__((ext_vector_type(8))) _Float16;
using floatx4 = __attribute__((ext_vector_type(4))) float;

// ---------------- prep: frag-major fp16 W1/W2 packs + zero deg ----------------
// Whp[((ks*4+ct)*64 + lane)*8 + j] = f16( W[(ks*32 + (lane>>4)*8 + j)*64 + ct*16 + (lane&15)] )
__global__ __launch_bounds__(256) void k_prep(const float* __restrict__ W1,
                                              const float* __restrict__ W2,
                                              __half* __restrict__ Whp1,
                                              __half* __restrict__ Whp2,
                                              int* __restrict__ deg) {
    const int blk = blockIdx.x;
    if (blk < 4) {                      // W1: K=128 -> 16 frags * 64 lanes = 1024 items
        int t = blk * 256 + threadIdx.x;
        int lane = t & 63, frag = t >> 6;
        int ks = frag >> 2, ct = frag & 3;
        int quad = lane >> 4, n = lane & 15;
        __half tmp[8];
#pragma unroll
        for (int j = 0; j < 8; ++j)
            tmp[j] = __float2half(W1[(ks * 32 + quad * 8 + j) * HID + ct * 16 + n]);
        *(uint4*)(Whp1 + t * 8) = *(uint4*)tmp;
    } else if (blk < 6) {               // W2: K=64 -> 8 frags * 64 = 512 items
        int t = (blk - 4) * 256 + threadIdx.x;
        int lane = t & 63, frag = t >> 6;
        int ks = frag >> 2, ct = frag & 3;
        int quad = lane >> 4, n = lane & 15;
        __half tmp[8];
#pragma unroll
        for (int j = 0; j < 8; ++j)
            tmp[j] = __float2half(W2[(ks * 32 + quad * 8 + j) * HID + ct * 16 + n]);
        *(uint4*)(Whp2 + t * 8) = *(uint4*)tmp;
    } else {                            // blocks 6..69 zero deg[NN]
        for (int i = (blk - 6) * 256 + threadIdx.x; i < NN; i += 64 * 256)
            deg[i] = 0;
    }
}

// ---------------- counting-sort CSR, pass 1: per-node in-degree ----------------
__global__ __launch_bounds__(256) void k_count(const int* __restrict__ dst,
                                               int* __restrict__ deg) {
    const int e = blockIdx.x * 256 + threadIdx.x;
    if (e < NE) atomicAdd(&deg[dst[e]], 1);
}

// ---------------- counting-sort CSR, pass 2: prefix scan + dinv ----------------
// One 1024-thread block; thread t owns nodes [t*98, t*98+98).
__global__ __launch_bounds__(1024) void k_scan(const int* __restrict__ deg,
                                               int* __restrict__ row_start,
                                               int* __restrict__ cur,
                                               float* __restrict__ dinv) {
    __shared__ int sh[1024];
    const int t = threadIdx.x;
    const int lo = t * 98;
    const int hi = (lo + 98 < NN) ? lo + 98 : NN;
    int s = 0;
    for (int v = lo; v < hi; ++v) s += deg[v];
    sh[t] = s;
    __syncthreads();
    int val = s;
    for (int off = 1; off < 1024; off <<= 1) {
        int add = (t >= off) ? sh[t - off] : 0;
        __syncthreads();
        val += add;
        sh[t] = val;
        __syncthreads();
    }
    int run = val - s;                  // exclusive prefix of this thread's chunk
    for (int v = lo; v < hi; ++v) {
        int d = deg[v];
        row_start[v] = run;
        cur[v] = run;
        dinv[v] = rsqrtf((float)(d + 1));  // +1 self loop
        run += d;
    }
    if (t == 0) row_start[NN] = NE;
}

// ---------------- counting-sort CSR, pass 3: scatter src into pack2 ----------------
__global__ __launch_bounds__(256) void k_scatter(const int* __restrict__ src,
                                                 const int* __restrict__ dst,
                                                 int* __restrict__ cur,
                                                 unsigned* __restrict__ pack2) {
    const int e = blockIdx.x * 256 + threadIdx.x;
    if (e < NE) {
        int pos = atomicAdd(&cur[dst[e]], 1);
        pack2[pos] = (unsigned)src[e];
    }
}

// ---------------- MFMA GEMM (layer 1): g1 = fp16( dinv * (x @ W1) ) ----------------
template <int K>
__global__ __launch_bounds__(256) void k_mm(const float* __restrict__ x,
                                            const __half* __restrict__ Whp,
                                            const float* __restrict__ dinv,
                                            __half* __restrict__ gout) {
    const int t = threadIdx.x;
    const int w = t >> 6, lane = t & 63;
    const int quad = lane >> 4, m = lane & 15;
    const int rowA = blockIdx.x * 64 + w * 16 + m;
    const bool rok = rowA < NN;
    const float* xr = x + (long)rowA * K + quad * 8;

    floatx4 acc[4] = {};
#pragma unroll
    for (int ks = 0; ks < K / 32; ++ks) {
        float xv[8];
        if (rok) {
            float4 p0 = *(const float4*)(xr + ks * 32);
            float4 p1 = *(const float4*)(xr + ks * 32 + 4);
            xv[0] = p0.x; xv[1] = p0.y; xv[2] = p0.z; xv[3] = p0.w;
            xv[4] = p1.x; xv[5] = p1.y; xv[6] = p1.z; xv[7] = p1.w;
        } else {
#pragma unroll
            for (int j = 0; j < 8; ++j) xv[j] = 0.f;
        }
        half8 a;
#pragma unroll
        for (int j = 0; j < 8; ++j) a[j] = (_Float16)xv[j];
#pragma unroll
        for (int ct = 0; ct < 4; ++ct) {
            half8 b = *(const half8*)(Whp + ((ks * 4 + ct) * 64 + lane) * 8);
            acc[ct] = __builtin_amdgcn_mfma_f32_16x16x32_f16(a, b, acc[ct], 0, 0, 0);
        }
    }

#pragma unroll
    for (int r = 0; r < 4; ++r) {
        int rowD = blockIdx.x * 64 + w * 16 + quad * 4 + r;
        if (rowD < NN) {
            float dv = dinv[rowD];
#pragma unroll
            for (int ct = 0; ct < 4; ++ct)
                gout[rowD * HID + ct * 16 + m] = __float2half(dv * acc[ct][r]);
        }
    }
}

// ---------------- FUSED agg1 + mm2: g2 = fp16( dinv * (relu(agg1+b1) @ W2) ) -------
// R7-proven gather (16 subs x 8 B x 4 slots) + R9/R10-verified metadata hoist.
__global__ __launch_bounds__(256) void k_aggmm(const unsigned* __restrict__ pack2,
                                               const int* __restrict__ row_start,
                                               const int* __restrict__ deg,
                                               const float* __restrict__ dinv,
                                               const __half* __restrict__ g1,
                                               const float* __restrict__ b1,
                                               const __half* __restrict__ Whp2,
                                               __half* __restrict__ g2) {
    __shared__ __half tile[16][72];
    const int w = threadIdx.x >> 6, lane = threadIdx.x & 63;
    const int sub = lane & 15, slot = lane >> 4;
    const int vbase = blockIdx.x * 16 + w * 4;
    const float4 bv = *(const float4*)(b1 + sub * 4);

    // hoisted per-wave node metadata (vbase % 4 == 0 -> 16B aligned)
    int4   rs4 = *(const int4*)(row_start + vbase);
    int4   dg4 = *(const int4*)(deg + vbase);
    float4 dv4 = *(const float4*)(dinv + vbase);
    const int   beg_i[4] = {rs4.x, rs4.y, rs4.z, rs4.w};
    const int   cnt_i[4] = {dg4.x, dg4.y, dg4.z, dg4.w};
    const float dv_i[4]  = {dv4.x, dv4.y, dv4.z, dv4.w};
    int pre[4];
#pragma unroll
    for (int i = 0; i < 4; ++i) {
        pre[i] = 0;
        if (lane < cnt_i[i]) pre[i] = (int)pack2[beg_i[i] + lane];
    }

#pragma unroll
    for (int i = 0; i < 4; ++i) {
        const int v = vbase + i;
        const int beg = beg_i[i];
        const int cnt = cnt_i[i];
        const int n0 = cnt < 64 ? cnt : 64;
        float4 acc = make_float4(0.f, 0.f, 0.f, 0.f);

        int k = 0;
        for (; k + 8 <= n0; k += 8) {              // uniform: all 64 lanes
            int sA = __shfl(pre[i], k + slot);
            int sB = __shfl(pre[i], k + 4 + slot);
            uint2 rA = *(const uint2*)(g1 + sA * HID + sub * 4);
            uint2 rB = *(const uint2*)(g1 + sB * HID + sub * 4);
            float2 a0 = __half22float2(*(const __half2*)&rA.x);
            float2 a1 = __half22float2(*(const __half2*)&rA.y);
            float2 b0 = __half22float2(*(const __half2*)&rB.x);
            float2 b1f = __half22float2(*(const __half2*)&rB.y);
            acc.x += a0.x + b0.x; acc.y += a0.y + b0.y;
            acc.z += a1.x + b1f.x; acc.w += a1.y + b1f.y;
        }
        for (; k < n0; k += 4) {                   // tail: shfl hoisted, clamped
            int idx  = k + slot;
            int idxc = idx < n0 ? idx : 0;
            int s = __shfl(pre[i], idxc);
            if (idx < n0) {
                uint2 r = *(const uint2*)(g1 + s * HID + sub * 4);
                float2 a0 = __half22float2(*(const __half2*)&r.x);
                float2 a1 = __half22float2(*(const __half2*)&r.y);
                acc.x += a0.x; acc.y += a0.y; acc.z += a1.x; acc.w += a1.y;
            }
        }
        for (int kk = 64 + slot; kk < cnt; kk += 4) {  // deg > 64: no shfl, safe
            int s = (int)pack2[beg + kk];
            uint2 r = *(const uint2*)(g1 + s * HID + sub * 4);
            float2 a0 = __half22float2(*(const __half2*)&r.x);
            float2 a1 = __half22float2(*(const __half2*)&r.y);
            acc.x += a0.x; acc.y += a0.y; acc.z += a1.x; acc.w += a1.y;
        }
#pragma unroll
        for (int mm = 16; mm <= 32; mm <<= 1) {
            acc.x += __shfl_xor(acc.x, mm);
            acc.y += __shfl_xor(acc.y, mm);
            acc.z += __shfl_xor(acc.z, mm);
            acc.w += __shfl_xor(acc.w, mm);
        }
        if (slot == 0) {                           // relu(out1) -> fp16 LDS row
            const float dv = dv_i[i];
            uint2 sr = *(const uint2*)(g1 + v * HID + sub * 4);
            float2 s0 = __half22float2(*(const __half2*)&sr.x);
            float2 s1 = __half22float2(*(const __half2*)&sr.y);
            __half tmp[4];
            tmp[0] = __float2half(fmaxf(dv * (acc.x + s0.x) + bv.x, 0.f));
            tmp[1] = __float2half(fmaxf(dv * (acc.y + s0.y) + bv.y, 0.f));
            tmp[2] = __float2half(fmaxf(dv * (acc.z + s1.x) + bv.z, 0.f));
            tmp[3] = __float2half(fmaxf(dv * (acc.w + s1.y) + bv.w, 0.f));
            *(uint2*)&tile[w * 4 + i][sub * 4] = *(uint2*)tmp;
        }
    }
    __syncthreads();

    // mm2: wave w computes col-tile ct = w of rows [block*16, block*16+16)
    const int quad = lane >> 4, m = lane & 15;
    floatx4 acc2 = {};
#pragma unroll
    for (int ks = 0; ks < 2; ++ks) {
        half8 a = *(const half8*)&tile[m][ks * 32 + quad * 8];
        half8 b = *(const half8*)(Whp2 + ((ks * 4 + w) * 64 + lane) * 8);
        acc2 = __builtin_amdgcn_mfma_f32_16x16x32_f16(a, b, acc2, 0, 0, 0);
    }
#pragma unroll
    for (int r = 0; r < 4; ++r) {
        int rowD = blockIdx.x * 16 + quad * 4 + r;
        g2[rowD * HID + w * 16 + m] = __float2half(dinv[rowD] * acc2[r]);
    }
}

// ---------------- final aggregation (layer 2): fp32 out (R7-verified) --------------
__global__ __launch_bounds__(256) void k_agg(const unsigned* __restrict__ pack2,
                                             const int* __restrict__ row_start,
                                             const int* __restrict__ deg,
                                             const float* __restrict__ dinv,
                                             const __half* __restrict__ g,
                                             const float* __restrict__ bias,
                                             float* __restrict__ out) {
    const int v = blockIdx.x * 4 + (threadIdx.x >> 6);
    if (v >= NN) return;
    const int lane = threadIdx.x & 63;
    const int sub  = lane & 15;
    const int slot = lane >> 4;
    const int beg = row_start[v];
    const int cnt = deg[v];
    int pre = 0;
    if (lane < cnt) pre = (int)pack2[beg + lane];
    const int n0 = cnt < 64 ? cnt : 64;
    float4 acc = make_float4(0.f, 0.f, 0.f, 0.f);

    int k = 0;
    for (; k + 8 <= n0; k += 8) {
        int sA = __shfl(pre, k + slot);
        int sB = __shfl(pre, k + 4 + slot);
        uint2 rA = *(const uint2*)(g + sA * HID + sub * 4);
        uint2 rB = *(const uint2*)(g + sB * HID + sub * 4);
        float2 a0 = __half22float2(*(const __half2*)&rA.x);
        float2 a1 = __half22float2(*(const __half2*)&rA.y);
        float2 b0 = __half22float2(*(const __half2*)&rB.x);
        float2 b1 = __half22float2(*(const __half2*)&rB.y);
        acc.x += a0.x + b0.x; acc.y += a0.y + b0.y;
        acc.z += a1.x + b1.x; acc.w += a1.y + b1.y;
    }
    for (; k < n0; k += 4) {
        int idx  = k + slot;
        int idxc = idx < n0 ? idx : 0;
        int s = __shfl(pre, idxc);
        if (idx < n0) {
            uint2 r = *(const uint2*)(g + s * HID + sub * 4);
            float2 a0 = __half22float2(*(const __half2*)&r.x);
            float2 a1 = __half22float2(*(const __half2*)&r.y);
            acc.x += a0.x; acc.y += a0.y; acc.z += a1.x; acc.w += a1.y;
        }
    }
    for (int kk = 64 + slot; kk < cnt; kk += 4) {
        int s = (int)pack2[beg + kk];
        uint2 r = *(const uint2*)(g + s * HID + sub * 4);
        float2 a0 = __half22float2(*(const __half2*)&r.x);
        float2 a1 = __half22float2(*(const __half2*)&r.y);
        acc.x += a0.x; acc.y += a0.y; acc.z += a1.x; acc.w += a1.y;
    }
#pragma unroll
    for (int mm = 16; mm <= 32; mm <<= 1) {
        acc.x += __shfl_xor(acc.x, mm);
        acc.y += __shfl_xor(acc.y, mm);
        acc.z += __shfl_xor(acc.z, mm);
        acc.w += __shfl_xor(acc.w, mm);
    }
    if (slot == 0) {
        const float dv = dinv[v];
        uint2 sr = *(const uint2*)(g + v * HID + sub * 4);
        float2 s0 = __half22float2(*(const __half2*)&sr.x);
        float2 s1 = __half22float2(*(const __half2*)&sr.y);
        float4 bv = *(const float4*)(bias + sub * 4);
        float4 o;
        o.x = dv * (acc.x + s0.x) + bv.x;
        o.y = dv * (acc.y + s0.y) + bv.y;
        o.z = dv * (acc.z + s1.x) + bv.z;
        o.w = dv * (acc.w + s1.y) + bv.w;
        *(float4*)(out + v * HID + sub * 4) = o;
    }
}

// ---------------- launch ----------------
extern "C" void kernel_launch(void* const* d_in, const int* in_sizes, int n_in,
                              void* d_out, int out_size, void* d_ws, size_t ws_size,
                              hipStream_t stream) {
    const float* x  = (const float*)d_in[0];
    const int*   ei = (const int*)d_in[1];
    const float* W1 = (const float*)d_in[2];
    const float* b1 = (const float*)d_in[3];
    const float* W2 = (const float*)d_in[4];
    const float* b2 = (const float*)d_in[5];
    float* out = (float*)d_out;
    (void)in_sizes; (void)n_in; (void)out_size; (void)ws_size;

    const int* src = ei;
    const int* dst = ei + NE;

    // Workspace (~33 MB of the 256 MiB ws):
    char* ws = (char*)d_ws;
    __half*   Whp1      = (__half*)(ws + 0x004000);  // 16 KB (frag-major W1)
    __half*   Whp2      = (__half*)(ws + 0x008000);  // 8 KB  (frag-major W2)
    float*    dinv      = (float*)(ws + 0x010000);   // 400 KB
    int*      row_start = (int*)(ws + 0x080000);     // 400 KB (+1 entry)
    int*      deg       = (int*)(ws + 0x100000);     // 400 KB
    int*      cur       = (int*)(ws + 0x180000);     // 400 KB (scatter cursors)
    unsigned* pack2     = (unsigned*)(ws + 0x200000);  // 5 MB (dense CSR src lists)
    __half*   g1        = (__half*)(ws + 0x1200000);   // 12.8 MB (fp16)
    __half*   g2        = (__half*)(ws + 0x2000000);   // 12.8 MB (fp16)

    // prep (W packs + deg zero), then counting-sort CSR: count -> scan -> scatter
    k_prep<<<70, 256, 0, stream>>>(W1, W2, Whp1, Whp2, deg);
    k_count<<<(NE + 255) / 256, 256, 0, stream>>>(dst, deg);
    k_scan<<<1, 1024, 0, stream>>>(deg, row_start, cur, dinv);
    k_scatter<<<(NE + 255) / 256, 256, 0, stream>>>(src, dst, cur, pack2);

    // layer 1 GEMM: g1 = fp16(dinv*(x @ W1))
    k_mm<KDIM><<<(NN + 63) / 64, 256, 0, stream>>>(x, Whp1, dinv, g1);
    // fused: agg1 (+b1, relu) -> mm2 -> g2 = fp16(dinv*(relu(out1) @ W2))
    k_aggmm<<<NN / 16, 256, 0, stream>>>(pack2, row_start, deg, dinv, g1, b1, Whp2, g2);
    // final agg: out = dinv*(sum g2 + g2_self) + b2
    k_agg<<<(NN + 3) / 4, 256, 0, stream>>>(pack2, row_start, deg, dinv, g2, b2, out);
}

// Round 12
// 209.070 us; speedup vs baseline: 2.8535x; 2.8535x over previous
//
#include <hip/hip_runtime.h>
#include <hip/hip_fp16.h>

constexpr int NN = 100000;   // nodes (== 6250 * 16, no remainder)
constexpr int NE = 1250000;  // edges
constexpr int KDIM = 128;    // IN_DIM
constexpr int HID = 64;

constexpr int NPB = 128;                      // nodes per bucket
constexpr int NB  = (NN + NPB - 1) / NPB;     // 782 buckets
constexpr int NBP = 1024;                     // padded bin count
constexpr int CAP = 2048;                     // fixed bucket capacity (mean 1600, sigma 40 -> 11 sigma)
constexpr int BIN_BLOCKS = 256;
constexpr int BIN_CHUNK  = (NE + BIN_BLOCKS - 1) / BIN_BLOCKS;  // 4883
constexpr int EPT = (BIN_CHUNK + 1023) / 1024;                  // 5 edges/thread

using half8   = __attribute__((ext_vector_type(8))) _Float16;
using floatx4 = __attribute__((ext_vector_type(4))) float;

// ---------------- prep: zero bucket cursors + frag-major fp16 W1/W2 packs ----------
__global__ __launch_bounds__(256) void k_prep(const float* __restrict__ W1,
                                              const float* __restrict__ W2,
                                              __half* __restrict__ Whp1,
                                              __half* __restrict__ Whp2,
                                              int* __restrict__ gcur) {
    const int blk = blockIdx.x;
    if (blk < 4) {                      // W1: K=128 -> 16 frags * 64 lanes = 1024 items
        int t = blk * 256 + threadIdx.x;
        int lane = t & 63, frag = t >> 6;
        int ks = frag >> 2, ct = frag & 3;
        int quad = lane >> 4, n = lane & 15;
        __half tmp[8];
#pragma unroll
        for (int j = 0; j < 8; ++j)
            tmp[j] = __float2half(W1[(ks * 32 + quad * 8 + j) * HID + ct * 16 + n]);
        *(uint4*)(Whp1 + t * 8) = *(uint4*)tmp;
    } else if (blk < 6) {               // W2: K=64 -> 8 frags * 64 = 512 items
        int t = (blk - 4) * 256 + threadIdx.x;
        int lane = t & 63, frag = t >> 6;
        int ks = frag >> 2, ct = frag & 3;
        int quad = lane >> 4, n = lane & 15;
        __half tmp[8];
#pragma unroll
        for (int j = 0; j < 8; ++j)
            tmp[j] = __float2half(W2[(ks * 32 + quad * 8 + j) * HID + ct * 16 + n]);
        *(uint4*)(Whp2 + t * 8) = *(uint4*)tmp;
    } else {                            // zero the bucket write cursors
        for (int i = threadIdx.x; i < NBP; i += 256) gcur[i] = 0;
    }
}

// ---------------- bin edges into fixed-capacity bucket regions of pack1 ------------
__global__ __launch_bounds__(1024) void k_bin(const int* __restrict__ src,
                                              const int* __restrict__ dst,
                                              int* __restrict__ gcur,
                                              unsigned* __restrict__ pack1) {
    __shared__ int cnt[NBP], rnk[NBP], gbase[NBP];
    const int t = threadIdx.x;
    for (int i = t; i < NBP; i += 1024) { cnt[i] = 0; rnk[i] = 0; }
    __syncthreads();
    const int c0 = blockIdx.x * BIN_CHUNK;
    int b[EPT];
    unsigned val[EPT];
#pragma unroll
    for (int i = 0; i < EPT; ++i) {
        int idx = i * 1024 + t;
        int e = c0 + idx;
        b[i] = -1;
        if (idx < BIN_CHUNK && e < NE) {
            int d = dst[e], s = src[e];
            int bb = d >> 7;
            b[i] = bb;
            val[i] = (unsigned)s | ((unsigned)(d & 127) << 17);
            atomicAdd(&cnt[bb], 1);
        }
    }
    __syncthreads();
    for (int i = t; i < NBP; i += 1024) {
        int c = cnt[i];
        if (c) gbase[i] = i * CAP + atomicAdd(&gcur[i], c);
    }
    __syncthreads();
#pragma unroll
    for (int i = 0; i < EPT; ++i) {
        if (b[i] >= 0) {
            int r = atomicAdd(&rnk[b[i]], 1);
            pack1[gbase[b[i]] + r] = val[i];
        }
    }
}

// ---------------- per-bucket sort: pack1 -> node-sorted pack2 + row_start/deg/dinv -
// R11b: bucket staged in LDS during histogram pass; scatter reads LDS (one global
// read of pack1 instead of two).
__global__ __launch_bounds__(256) void k_sort(const unsigned* __restrict__ pack1,
                                              const int* __restrict__ gcur,
                                              unsigned* __restrict__ pack2,
                                              int* __restrict__ row_start,
                                              int* __restrict__ deg,
                                              float* __restrict__ dinv) {
    __shared__ int h[NPB];        // counts, then write cursors
    __shared__ int sh[NPB];       // scan scratch
    __shared__ unsigned ld[CAP];  // staged bucket (<= 2048 entries, bound pre-exists)
    const int t = threadIdx.x;
    const int bkt = blockIdx.x;
    if (t < NPB) h[t] = 0;
    __syncthreads();
    const int beg = bkt * CAP;
    const int n = gcur[bkt];
    for (int i = t; i < n; i += 256) {
        unsigned p = pack1[beg + i];
        ld[i] = p;
        atomicAdd(&h[(p >> 17) & 127], 1);
    }
    __syncthreads();
    int v0 = 0;
    if (t < NPB) { v0 = h[t]; sh[t] = v0; }
    __syncthreads();
    int val = v0;
    for (int off = 1; off < NPB; off <<= 1) {
        int add = (t < NPB && t >= off) ? sh[t - off] : 0;
        __syncthreads();
        if (t < NPB) { val += add; sh[t] = val; }
        __syncthreads();
    }
    if (t < NPB) {
        int start = beg + (val - v0);
        int node = bkt * NPB + t;
        if (node < NN) {
            row_start[node] = start;
            deg[node] = v0;
            dinv[node] = rsqrtf((float)(v0 + 1));
        }
        h[t] = start;
    }
    __syncthreads();
    for (int i = t; i < n; i += 256) {
        unsigned p = ld[i];
        int pos = atomicAdd(&h[(p >> 17) & 127], 1);
        pack2[pos] = p & 0x1FFFF;
    }
}

// ---------------- MFMA GEMM (layer 1): g1 = fp16( dinv * (x @ W1) ) ----------------
template <int K>
__global__ __launch_bounds__(256) void k_mm(const float* __restrict__ x,
                                            const __half* __restrict__ Whp,
                                            const float* __restrict__ dinv,
                                            __half* __restrict__ gout) {
    const int t = threadIdx.x;
    const int w = t >> 6, lane = t & 63;
    const int quad = lane >> 4, m = lane & 15;
    const int rowA = blockIdx.x * 64 + w * 16 + m;
    const bool rok = rowA < NN;
    const float* xr = x + (long)rowA * K + quad * 8;

    floatx4 acc[4] = {};
#pragma unroll
    for (int ks = 0; ks < K / 32; ++ks) {
        float xv[8];
        if (rok) {
            float4 p0 = *(const float4*)(xr + ks * 32);
            float4 p1 = *(const float4*)(xr + ks * 32 + 4);
            xv[0] = p0.x; xv[1] = p0.y; xv[2] = p0.z; xv[3] = p0.w;
            xv[4] = p1.x; xv[5] = p1.y; xv[6] = p1.z; xv[7] = p1.w;
        } else {
#pragma unroll
            for (int j = 0; j < 8; ++j) xv[j] = 0.f;
        }
        half8 a;
#pragma unroll
        for (int j = 0; j < 8; ++j) a[j] = (_Float16)xv[j];
#pragma unroll
        for (int ct = 0; ct < 4; ++ct) {
            half8 b = *(const half8*)(Whp + ((ks * 4 + ct) * 64 + lane) * 8);
            acc[ct] = __builtin_amdgcn_mfma_f32_16x16x32_f16(a, b, acc[ct], 0, 0, 0);
        }
    }

#pragma unroll
    for (int r = 0; r < 4; ++r) {
        int rowD = blockIdx.x * 64 + w * 16 + quad * 4 + r;
        if (rowD < NN) {
            float dv = dinv[rowD];
#pragma unroll
            for (int ct = 0; ct < 4; ++ct)
                gout[rowD * HID + ct * 16 + m] = __float2half(dv * acc[ct][r]);
        }
    }
}

// ---------------- FUSED agg1 + mm2: g2 = fp16( dinv * (relu(agg1+b1) @ W2) ) -------
// R7-proven gather (16 subs x 8 B x 4 slots) + R9/R10-verified metadata hoist.
__global__ __launch_bounds__(256) void k_aggmm(const unsigned* __restrict__ pack2,
                                               const int* __restrict__ row_start,
                                               const int* __restrict__ deg,
                                               const float* __restrict__ dinv,
                                               const __half* __restrict__ g1,
                                               const float* __restrict__ b1,
                                               const __half* __restrict__ Whp2,
                                               __half* __restrict__ g2) {
    __shared__ __half tile[16][72];
    const int w = threadIdx.x >> 6, lane = threadIdx.x & 63;
    const int sub = lane & 15, slot = lane >> 4;
    const int vbase = blockIdx.x * 16 + w * 4;
    const float4 bv = *(const float4*)(b1 + sub * 4);

    // hoisted per-wave node metadata (vbase % 4 == 0 -> 16B aligned)
    int4   rs4 = *(const int4*)(row_start + vbase);
    int4   dg4 = *(const int4*)(deg + vbase);
    float4 dv4 = *(const float4*)(dinv + vbase);
    const int   beg_i[4] = {rs4.x, rs4.y, rs4.z, rs4.w};
    const int   cnt_i[4] = {dg4.x, dg4.y, dg4.z, dg4.w};
    const float dv_i[4]  = {dv4.x, dv4.y, dv4.z, dv4.w};
    int pre[4];
#pragma unroll
    for (int i = 0; i < 4; ++i) {
        pre[i] = 0;
        if (lane < cnt_i[i]) pre[i] = (int)pack2[beg_i[i] + lane];
    }

#pragma unroll
    for (int i = 0; i < 4; ++i) {
        const int v = vbase + i;
        const int beg = beg_i[i];
        const int cnt = cnt_i[i];
        const int n0 = cnt < 64 ? cnt : 64;
        float4 acc = make_float4(0.f, 0.f, 0.f, 0.f);

        int k = 0;
        for (; k + 8 <= n0; k += 8) {              // uniform: all 64 lanes
            int sA = __shfl(pre[i], k + slot);
            int sB = __shfl(pre[i], k + 4 + slot);
            uint2 rA = *(const uint2*)(g1 + sA * HID + sub * 4);
            uint2 rB = *(const uint2*)(g1 + sB * HID + sub * 4);
            float2 a0 = __half22float2(*(const __half2*)&rA.x);
            float2 a1 = __half22float2(*(const __half2*)&rA.y);
            float2 b0 = __half22float2(*(const __half2*)&rB.x);
            float2 b1f = __half22float2(*(const __half2*)&rB.y);
            acc.x += a0.x + b0.x; acc.y += a0.y + b0.y;
            acc.z += a1.x + b1f.x; acc.w += a1.y + b1f.y;
        }
        for (; k < n0; k += 4) {                   // tail: shfl hoisted, clamped
            int idx  = k + slot;
            int idxc = idx < n0 ? idx : 0;
            int s = __shfl(pre[i], idxc);
            if (idx < n0) {
                uint2 r = *(const uint2*)(g1 + s * HID + sub * 4);
                float2 a0 = __half22float2(*(const __half2*)&r.x);
                float2 a1 = __half22float2(*(const __half2*)&r.y);
                acc.x += a0.x; acc.y += a0.y; acc.z += a1.x; acc.w += a1.y;
            }
        }
        for (int kk = 64 + slot; kk < cnt; kk += 4) {  // deg > 64: no shfl, safe
            int s = (int)pack2[beg + kk];
            uint2 r = *(const uint2*)(g1 + s * HID + sub * 4);
            float2 a0 = __half22float2(*(const __half2*)&r.x);
            float2 a1 = __half22float2(*(const __half2*)&r.y);
            acc.x += a0.x; acc.y += a0.y; acc.z += a1.x; acc.w += a1.y;
        }
#pragma unroll
        for (int mm = 16; mm <= 32; mm <<= 1) {
            acc.x += __shfl_xor(acc.x, mm);
            acc.y += __shfl_xor(acc.y, mm);
            acc.z += __shfl_xor(acc.z, mm);
            acc.w += __shfl_xor(acc.w, mm);
        }
        if (slot == 0) {                           // relu(out1) -> fp16 LDS row
            const float dv = dv_i[i];
            uint2 sr = *(const uint2*)(g1 + v * HID + sub * 4);
            float2 s0 = __half22float2(*(const __half2*)&sr.x);
            float2 s1 = __half22float2(*(const __half2*)&sr.y);
            __half tmp[4];
            tmp[0] = __float2half(fmaxf(dv * (acc.x + s0.x) + bv.x, 0.f));
            tmp[1] = __float2half(fmaxf(dv * (acc.y + s0.y) + bv.y, 0.f));
            tmp[2] = __float2half(fmaxf(dv * (acc.z + s1.x) + bv.z, 0.f));
            tmp[3] = __float2half(fmaxf(dv * (acc.w + s1.y) + bv.w, 0.f));
            *(uint2*)&tile[w * 4 + i][sub * 4] = *(uint2*)tmp;
        }
    }
    __syncthreads();

    // mm2: wave w computes col-tile ct = w of rows [block*16, block*16+16)
    const int quad = lane >> 4, m = lane & 15;
    floatx4 acc2 = {};
#pragma unroll
    for (int ks = 0; ks < 2; ++ks) {
        half8 a = *(const half8*)&tile[m][ks * 32 + quad * 8];
        half8 b = *(const half8*)(Whp2 + ((ks * 4 + w) * 64 + lane) * 8);
        acc2 = __builtin_amdgcn_mfma_f32_16x16x32_f16(a, b, acc2, 0, 0, 0);
    }
#pragma unroll
    for (int r = 0; r < 4; ++r) {
        int rowD = blockIdx.x * 16 + quad * 4 + r;
        g2[rowD * HID + w * 16 + m] = __float2half(dinv[rowD] * acc2[r]);
    }
}

// ---------------- final aggregation (layer 2): fp32 out (R7-verified) --------------
__global__ __launch_bounds__(256) void k_agg(const unsigned* __restrict__ pack2,
                                             const int* __restrict__ row_start,
                                             const int* __restrict__ deg,
                                             const float* __restrict__ dinv,
                                             const __half* __restrict__ g,
                                             const float* __restrict__ bias,
                                             float* __restrict__ out) {
    const int v = blockIdx.x * 4 + (threadIdx.x >> 6);
    if (v >= NN) return;
    const int lane = threadIdx.x & 63;
    const int sub  = lane & 15;
    const int slot = lane >> 4;
    const int beg = row_start[v];
    const int cnt = deg[v];
    int pre = 0;
    if (lane < cnt) pre = (int)pack2[beg + lane];
    const int n0 = cnt < 64 ? cnt : 64;
    float4 acc = make_float4(0.f, 0.f, 0.f, 0.f);

    int k = 0;
    for (; k + 8 <= n0; k += 8) {
        int sA = __shfl(pre, k + slot);
        int sB = __shfl(pre, k + 4 + slot);
        uint2 rA = *(const uint2*)(g + sA * HID + sub * 4);
        uint2 rB = *(const uint2*)(g + sB * HID + sub * 4);
        float2 a0 = __half22float2(*(const __half2*)&rA.x);
        float2 a1 = __half22float2(*(const __half2*)&rA.y);
        float2 b0 = __half22float2(*(const __half2*)&rB.x);
        float2 b1 = __half22float2(*(const __half2*)&rB.y);
        acc.x += a0.x + b0.x; acc.y += a0.y + b0.y;
        acc.z += a1.x + b1.x; acc.w += a1.y + b1.y;
    }
    for (; k < n0; k += 4) {
        int idx  = k + slot;
        int idxc = idx < n0 ? idx : 0;
        int s = __shfl(pre, idxc);
        if (idx < n0) {
            uint2 r = *(const uint2*)(g + s * HID + sub * 4);
            float2 a0 = __half22float2(*(const __half2*)&r.x);
            float2 a1 = __half22float2(*(const __half2*)&r.y);
            acc.x += a0.x; acc.y += a0.y; acc.z += a1.x; acc.w += a1.y;
        }
    }
    for (int kk = 64 + slot; kk < cnt; kk += 4) {
        int s = (int)pack2[beg + kk];
        uint2 r = *(const uint2*)(g + s * HID + sub * 4);
        float2 a0 = __half22float2(*(const __half2*)&r.x);
        float2 a1 = __half22float2(*(const __half2*)&r.y);
        acc.x += a0.x; acc.y += a0.y; acc.z += a1.x; acc.w += a1.y;
    }
#pragma unroll
    for (int mm = 16; mm <= 32; mm <<= 1) {
        acc.x += __shfl_xor(acc.x, mm);
        acc.y += __shfl_xor(acc.y, mm);
        acc.z += __shfl_xor(acc.z, mm);
        acc.w += __shfl_xor(acc.w, mm);
    }
    if (slot == 0) {
        const float dv = dinv[v];
        uint2 sr = *(const uint2*)(g + v * HID + sub * 4);
        float2 s0 = __half22float2(*(const __half2*)&sr.x);
        float2 s1 = __half22float2(*(const __half2*)&sr.y);
        float4 bv = *(const float4*)(bias + sub * 4);
        float4 o;
        o.x = dv * (acc.x + s0.x) + bv.x;
        o.y = dv * (acc.y + s0.y) + bv.y;
        o.z = dv * (acc.z + s1.x) + bv.z;
        o.w = dv * (acc.w + s1.y) + bv.w;
        *(float4*)(out + v * HID + sub * 4) = o;
    }
}

// ---------------- launch ----------------
extern "C" void kernel_launch(void* const* d_in, const int* in_sizes, int n_in,
                              void* d_out, int out_size, void* d_ws, size_t ws_size,
                              hipStream_t stream) {
    const float* x  = (const float*)d_in[0];
    const int*   ei = (const int*)d_in[1];
    const float* W1 = (const float*)d_in[2];
    const float* b1 = (const float*)d_in[3];
    const float* W2 = (const float*)d_in[4];
    const float* b2 = (const float*)d_in[5];
    float* out = (float*)d_out;
    (void)in_sizes; (void)n_in; (void)out_size; (void)ws_size;

    const int* src = ei;
    const int* dst = ei + NE;

    // Workspace (~43 MB of the 256 MiB ws):
    char* ws = (char*)d_ws;
    int*      gcur      = (int*)(ws + 0x000000);     // 4 KB (bucket cursors / counts)
    __half*   Whp1      = (__half*)(ws + 0x004000);  // 16 KB (frag-major W1)
    __half*   Whp2      = (__half*)(ws + 0x008000);  // 8 KB  (frag-major W2)
    float*    dinv      = (float*)(ws + 0x010000);   // 400 KB
    int*      row_start = (int*)(ws + 0x080000);     // 400 KB
    int*      deg       = (int*)(ws + 0x100000);     // 400 KB
    unsigned* pack1     = (unsigned*)(ws + 0x200000);  // 8 MB (1024 buckets x 2048)
    unsigned* pack2     = (unsigned*)(ws + 0xA00000);  // 8 MB (same layout)
    __half*   g1        = (__half*)(ws + 0x1200000);   // 12.8 MB (fp16)
    __half*   g2        = (__half*)(ws + 0x2000000);   // 12.8 MB (fp16)

    // prep (W packs + cursor zero) and CSR build (fixed-capacity buckets)
    k_prep<<<7, 256, 0, stream>>>(W1, W2, Whp1, Whp2, gcur);
    k_bin<<<BIN_BLOCKS, 1024, 0, stream>>>(src, dst, gcur, pack1);
    k_sort<<<NB, 256, 0, stream>>>(pack1, gcur, pack2, row_start, deg, dinv);

    // layer 1 GEMM: g1 = fp16(dinv*(x @ W1))
    k_mm<KDIM><<<(NN + 63) / 64, 256, 0, stream>>>(x, Whp1, dinv, g1);
    // fused: agg1 (+b1, relu) -> mm2 -> g2 = fp16(dinv*(relu(out1) @ W2))
    k_aggmm<<<NN / 16, 256, 0, stream>>>(pack2, row_start, deg, dinv, g1, b1, Whp2, g2);
    // final agg: out = dinv*(sum g2 + g2_self) + b2
    k_agg<<<(NN + 3) / 4, 256, 0, stream>>>(pack2, row_start, deg, dinv, g2, b2, out);
}